// Round 4
// baseline (571.252 us; speedup 1.0000x reference)
//
#include <hip/hip_runtime.h>

#define NN 10000
#define NE 640000
#define D 128
#define NF (NN * D)

// ---------------- CSR build ----------------

__global__ void zero_cnt_kernel(int* __restrict__ cnt) {
    int i = blockIdx.x * 256 + threadIdx.x;
    if (i < NN) cnt[i] = 0;
}

__global__ void hist_kernel(const int* __restrict__ ei, int* __restrict__ cnt) {
    int e = blockIdx.x * 256 + threadIdx.x;
    if (e < NE) atomicAdd(&cnt[ei[NE + e]], 1);
}

__global__ void scan_kernel(const int* __restrict__ cnt, int* __restrict__ row_ptr,
                            int* __restrict__ cursor) {
    __shared__ int lds[256];
    int t = threadIdx.x;
    const int CH = (NN + 255) / 256;  // 40
    int base = t * CH;
    int s = 0;
    for (int i = 0; i < CH; i++) {
        int idx = base + i;
        if (idx < NN) s += cnt[idx];
    }
    lds[t] = s;
    __syncthreads();
    for (int off = 1; off < 256; off <<= 1) {
        int v = (t >= off) ? lds[t - off] : 0;
        __syncthreads();
        lds[t] += v;
        __syncthreads();
    }
    int run = (t == 0) ? 0 : lds[t - 1];
    for (int i = 0; i < CH; i++) {
        int idx = base + i;
        if (idx < NN) {
            row_ptr[idx] = run;
            cursor[idx] = run;
            run += cnt[idx];
        }
    }
    if (t == 255) row_ptr[NN] = lds[255];
}

// meta[pos] = {src as int-bits, edge weight} — one 8B record per edge
__global__ void scatter_kernel(const int* __restrict__ ei, const float* __restrict__ conf,
                               int* __restrict__ cursor, float2* __restrict__ meta) {
    int e = blockIdx.x * 256 + threadIdx.x;
    if (e >= NE) return;
    int s = ei[e];
    int d = ei[NE + e];
    int pos = atomicAdd(&cursor[d], 1);
    meta[pos] = make_float2(__int_as_float(s), expf(-fabsf(conf[s] - conf[d])));
}

// ---------------- fused 2-layer MLP: C = (relu(A@W1+b1))@W2 + b2 ----------------
// 64-row tile, 16 rows per wave (2x the FMA per W-byte vs 8 rows/wave).
// One 32 KiB LDS buffer holds A during stage 1, then is overwritten with T
// (A is dead after stage 1). Output in PAIRED layout: features (c, c+64)
// adjacent as float2 at C[r*128 + 2*c] so the aggregate gather is one dwordx2.

__global__ __launch_bounds__(256) void mlp_pair_kernel(
    const float* __restrict__ A,
    const float* __restrict__ W1a, const float* __restrict__ b1a,
    const float* __restrict__ W2a, const float* __restrict__ b2a, float* __restrict__ Ca,
    const float* __restrict__ W1b, const float* __restrict__ b1b,
    const float* __restrict__ W2b, const float* __restrict__ b2b, float* __restrict__ Cb,
    int M) {
    const float* W1 = blockIdx.y ? W1b : W1a;
    const float* b1 = blockIdx.y ? b1b : b1a;
    const float* W2 = blockIdx.y ? W2b : W2a;
    const float* b2 = blockIdx.y ? b2b : b2a;
    float* C = blockIdx.y ? Cb : Ca;

    __shared__ float Sl[64][D];   // 32 KiB: A tile, then T tile
    int t = threadIdx.x;
    int row0 = blockIdx.x * 64;
    for (int i = t; i < 64 * D; i += 256) {
        int r = row0 + (i >> 7);
        Sl[i >> 7][i & 127] = (r < M) ? A[(size_t)r * D + (i & 127)] : 0.f;
    }
    __syncthreads();

    int tc = t & 63;   // cols {tc, tc+64}
    int tg = t >> 6;   // rows tg*16 .. tg*16+15 (LDS A reads broadcast within wave)

    // ---- stage 1 ----
    float acc0[16], acc1[16];
#pragma unroll
    for (int i = 0; i < 16; i++) { acc0[i] = 0.f; acc1[i] = 0.f; }
#pragma unroll 2
    for (int k = 0; k < D; k += 4) {
        float w0[4], w1[4];
#pragma unroll
        for (int kk = 0; kk < 4; kk++) {
            w0[kk] = W1[(k + kk) * D + tc];
            w1[kk] = W1[(k + kk) * D + tc + 64];
        }
#pragma unroll
        for (int i = 0; i < 16; i++) {
            float4 a = *(const float4*)&Sl[tg * 16 + i][k];
            acc0[i] = fmaf(a.x, w0[0], fmaf(a.y, w0[1], fmaf(a.z, w0[2], fmaf(a.w, w0[3], acc0[i]))));
            acc1[i] = fmaf(a.x, w1[0], fmaf(a.y, w1[1], fmaf(a.z, w1[2], fmaf(a.w, w1[3], acc1[i]))));
        }
    }
    float bv0 = b1[tc], bv1 = b1[tc + 64];
    __syncthreads();   // everyone done reading A
#pragma unroll
    for (int i = 0; i < 16; i++) {
        Sl[tg * 16 + i][tc] = fmaxf(acc0[i] + bv0, 0.f);
        Sl[tg * 16 + i][tc + 64] = fmaxf(acc1[i] + bv1, 0.f);
    }
    __syncthreads();

    // ---- stage 2 ----
    float d0[16], d1[16];
#pragma unroll
    for (int i = 0; i < 16; i++) { d0[i] = 0.f; d1[i] = 0.f; }
#pragma unroll 2
    for (int k = 0; k < D; k += 4) {
        float w0[4], w1[4];
#pragma unroll
        for (int kk = 0; kk < 4; kk++) {
            w0[kk] = W2[(k + kk) * D + tc];
            w1[kk] = W2[(k + kk) * D + tc + 64];
        }
#pragma unroll
        for (int i = 0; i < 16; i++) {
            float4 a = *(const float4*)&Sl[tg * 16 + i][k];
            d0[i] = fmaf(a.x, w0[0], fmaf(a.y, w0[1], fmaf(a.z, w0[2], fmaf(a.w, w0[3], d0[i]))));
            d1[i] = fmaf(a.x, w1[0], fmaf(a.y, w1[1], fmaf(a.z, w1[2], fmaf(a.w, w1[3], d1[i]))));
        }
    }
    float cb0 = b2[tc], cb1 = b2[tc + 64];
#pragma unroll
    for (int i = 0; i < 16; i++) {
        int r = row0 + tg * 16 + i;
        if (r < M) {
            float2 v;
            v.x = d0[i] + cb0;   // feature tc
            v.y = d1[i] + cb1;   // feature tc+64
            *(float2*)&C[(size_t)r * D + 2 * tc] = v;
        }
    }
}

// ---------------- CSR aggregate: one block (4 waves) per dst node ----------------
// Each wave takes a contiguous quarter of the node's edges, unrolled x4 with
// independent accumulators -> up to 16 gathers in flight per block.

__global__ __launch_bounds__(256) void aggregate_kernel(
    const float2* __restrict__ Mmsg2, const float* __restrict__ Mself,
    const int* __restrict__ row_ptr, const float2* __restrict__ meta,
    float* __restrict__ out) {
    int n = blockIdx.x;
    int t = threadIdx.x;
    int w = t >> 6, lane = t & 63;
    int beg = row_ptr[n], end = row_ptr[n + 1];
    int len = end - beg;
    int chunk = (len + 3) >> 2;
    int j0 = beg + w * chunk;
    int j1 = min(j0 + chunk, end);

    float a0[4] = {0.f, 0.f, 0.f, 0.f};
    float a1[4] = {0.f, 0.f, 0.f, 0.f};
    for (int j = j0; j < j1; j += 4) {
        float2 m[4];
#pragma unroll
        for (int u = 0; u < 4; u++) {
            int jj = j + u;
            m[u] = (jj < j1) ? meta[jj] : make_float2(__int_as_float(0), 0.f);
        }
        float2 g[4];
#pragma unroll
        for (int u = 0; u < 4; u++) g[u] = Mmsg2[(size_t)__float_as_int(m[u].x) * 64 + lane];
#pragma unroll
        for (int u = 0; u < 4; u++) {
            a0[u] = fmaf(m[u].y, g[u].x, a0[u]);
            a1[u] = fmaf(m[u].y, g[u].y, a1[u]);
        }
    }
    float b0 = (a0[0] + a0[1]) + (a0[2] + a0[3]);
    float b1 = (a1[0] + a1[1]) + (a1[2] + a1[3]);

    __shared__ float2 part[4][64];
    part[w][lane] = make_float2(b0, b1);
    __syncthreads();
    if (t < D) {
        int c = (t >> 1) + 64 * (t & 1);   // paired flat idx t -> canonical feature c
        const float* p = &part[0][0].x;
        float v = p[t] + p[D + t] + p[2 * D + t] + p[3 * D + t] + Mself[(size_t)n * D + t];
        out[(size_t)n * D + c] = fmaxf(v, 0.f);
    }
}

// ---------------- fused scoring + softmax + weighted sum ----------------
// Per 32-row tile: keep all 3 layer tiles in LDS (48 KiB), compute the 3
// per-layer scores (stage-1 GEMM + dot with w2 straight from registers via
// butterfly shuffle), then softmax over layers and the weighted sum.

__global__ __launch_bounds__(256) void score_finalize_kernel(
    const float* __restrict__ st, const float* __restrict__ W1,
    const float* __restrict__ b1, const float* __restrict__ w2,
    const float* __restrict__ b2, float* __restrict__ out, float* __restrict__ lw_out) {
    __shared__ float Al[3][32][D];   // 48 KiB
    int t = threadIdx.x;
    int row0 = blockIdx.x * 32;
    for (int l = 0; l < 3; l++)
        for (int i = t; i < 32 * D; i += 256) {
            int r = row0 + (i >> 7);
            Al[l][i >> 7][i & 127] =
                (r < NN) ? st[(size_t)l * NF + (size_t)r * D + (i & 127)] : 0.f;
        }
    __syncthreads();

    int tc = t & 63, tg = t >> 6;
    float w2a = w2[tc], w2b = w2[tc + 64];
    float bb = b2[0];
    float sc[3][8];

    for (int l = 0; l < 3; l++) {
        float acc0[8] = {0, 0, 0, 0, 0, 0, 0, 0};
        float acc1[8] = {0, 0, 0, 0, 0, 0, 0, 0};
#pragma unroll 2
        for (int k = 0; k < D; k += 4) {
            float w0[4], w1[4];
#pragma unroll
            for (int kk = 0; kk < 4; kk++) {
                w0[kk] = W1[(k + kk) * D + tc];
                w1[kk] = W1[(k + kk) * D + tc + 64];
            }
#pragma unroll
            for (int i = 0; i < 8; i++) {
                float4 a = *(const float4*)&Al[l][tg * 8 + i][k];
                acc0[i] = fmaf(a.x, w0[0], fmaf(a.y, w0[1], fmaf(a.z, w0[2], fmaf(a.w, w0[3], acc0[i]))));
                acc1[i] = fmaf(a.x, w1[0], fmaf(a.y, w1[1], fmaf(a.z, w1[2], fmaf(a.w, w1[3], acc1[i]))));
            }
        }
        float bv0 = b1[tc], bv1 = b1[tc + 64];
#pragma unroll
        for (int i = 0; i < 8; i++) {
            float p = fmaxf(acc0[i] + bv0, 0.f) * w2a + fmaxf(acc1[i] + bv1, 0.f) * w2b;
#pragma unroll
            for (int off = 1; off < 64; off <<= 1) p += __shfl_xor(p, off);
            sc[l][i] = p + bb;   // all lanes hold the row score
        }
    }

#pragma unroll
    for (int i = 0; i < 8; i++) {
        int r = row0 + tg * 8 + i;
        if (r >= NN) continue;
        float s0 = sc[0][i], s1 = sc[1][i], s2 = sc[2][i];
        float m = fmaxf(s0, fmaxf(s1, s2));
        float e0 = expf(s0 - m), e1 = expf(s1 - m), e2 = expf(s2 - m);
        float inv = 1.f / (e0 + e1 + e2);
        float wl0 = e0 * inv, wl1 = e1 * inv, wl2 = e2 * inv;
        int ri = tg * 8 + i;
        out[(size_t)r * D + tc] =
            wl0 * Al[0][ri][tc] + wl1 * Al[1][ri][tc] + wl2 * Al[2][ri][tc];
        out[(size_t)r * D + tc + 64] =
            wl0 * Al[0][ri][tc + 64] + wl1 * Al[1][ri][tc + 64] + wl2 * Al[2][ri][tc + 64];
        if (tc == 0) {
            lw_out[r] = wl0;
            lw_out[NN + r] = wl1;
            lw_out[2 * NN + r] = wl2;
        }
    }
}

extern "C" void kernel_launch(void* const* d_in, const int* in_sizes, int n_in,
                              void* d_out, int out_size, void* d_ws, size_t ws_size,
                              hipStream_t stream) {
    const float* x = (const float*)d_in[0];
    const int* ei = (const int*)d_in[1];
    const float* conf = (const float*)d_in[2];
    const float* msg_W1 = (const float*)d_in[3];
    const float* msg_b1 = (const float*)d_in[4];
    const float* msg_W2 = (const float*)d_in[5];
    const float* msg_b2 = (const float*)d_in[6];
    const float* self_W1 = (const float*)d_in[7];
    const float* self_b1 = (const float*)d_in[8];
    const float* self_W2 = (const float*)d_in[9];
    const float* self_b2 = (const float*)d_in[10];
    const float* score_W1 = (const float*)d_in[11];
    const float* score_b1 = (const float*)d_in[12];
    const float* score_W2 = (const float*)d_in[13];
    const float* score_b2 = (const float*)d_in[14];

    float* out = (float*)d_out;                 // [NN,D]
    float* out_stacked = out + NF;              // [3,NN,D]  (canonical, graded)
    float* out_lw = out + 4 * (size_t)NF;       // [3,NN]

    float* w = (float*)d_ws;
    float* Mmsg = w;                            // NF (paired layout)
    float* Mself = w + 1 * (size_t)NF;          // NF (paired layout)
    float2* meta = (float2*)(w + 2 * (size_t)NF);  // NE x {src, weight}
    int* row_ptr = (int*)(meta + NE);           // NN+1
    int* cnt = row_ptr + NN + 1;                // NN
    int* cursor = cnt + NN;                     // NN

    const int GE = (NE + 255) / 256;
    const int GN = (NN + 255) / 256;
    const int GB64 = (NN + 63) / 64;            // 157
    const int GB32 = (NN + 31) / 32;            // 313

    zero_cnt_kernel<<<GN, 256, 0, stream>>>(cnt);
    hist_kernel<<<GE, 256, 0, stream>>>(ei, cnt);
    scan_kernel<<<1, 256, 0, stream>>>(cnt, row_ptr, cursor);
    scatter_kernel<<<GE, 256, 0, stream>>>(ei, conf, cursor, meta);

    for (int l = 0; l < 3; l++) {
        const float* h_in = (l == 0) ? x : out_stacked + (size_t)(l - 1) * NF;
        mlp_pair_kernel<<<dim3(GB64, 2), 256, 0, stream>>>(
            h_in,
            msg_W1 + (size_t)l * D * D, msg_b1 + (size_t)l * D,
            msg_W2 + (size_t)l * D * D, msg_b2 + (size_t)l * D, Mmsg,
            self_W1 + (size_t)l * D * D, self_b1 + (size_t)l * D,
            self_W2 + (size_t)l * D * D, self_b2 + (size_t)l * D, Mself,
            NN);
        aggregate_kernel<<<NN, 256, 0, stream>>>((const float2*)Mmsg, Mself, row_ptr,
                                                 meta, out_stacked + (size_t)l * NF);
    }

    score_finalize_kernel<<<GB32, 256, 0, stream>>>(out_stacked, score_W1, score_b1,
                                                    score_W2, score_b2, out, out_lw);
}